// Round 4
// baseline (138.260 us; speedup 1.0000x reference)
//
#include <hip/hip_runtime.h>
#include <hip/hip_bf16.h>
#include <cstdint>
#include <math.h>

// Shapes: B=256, P=128, K=512, HE=1024, HF=512 (2HF=1024), D=2560, HID=64
// Outputs: embeddings (256,1,1536) then weights (256,128), fp32, flat-concat.
//
// R3 structure: prep (proj split-4 + W1k repack) -> K1 scores (512 blocks,
// 2/CU) -> K2 softmax+context (high-occupancy, keys re-read from L3 as fp32).

typedef __bf16 bf16;
typedef __attribute__((ext_vector_type(8))) __bf16 bf16x8;
typedef __attribute__((ext_vector_type(4))) __bf16 bf16x4;
typedef __attribute__((ext_vector_type(4))) float f32x4;

#define NB 256
#define NP 128
#define NK 512
#define SKLD 520   // keys LDS row stride (bf16): row stride 1040B -> rows alias 2-way (free)
#define K1_SK_BYTES (64 * SKLD * 2)                   // 66560
#define K1_SMEM (K1_SK_BYTES + 64*4 + 64*4)           // + projl + w2l = 67072 (2 blocks/CU)

// ---------------- prep: proj GEMV (4 blocks/batch) + W1k repack ----------------
// blocks 0..1023  : proj_part[q4][b][h], 128-deep chains (latency-spread)
// blocks 1024..1039: W1kT[h][k] = bf16(W1[k*64+h]) via LDS transpose
__global__ __launch_bounds__(256) void prep_kernel(
    const float* __restrict__ query, const float* __restrict__ frame,
    const float* __restrict__ W1, bf16* __restrict__ w1kt,
    float* __restrict__ proj_part)
{
    const int blk = blockIdx.x;
    const int t = threadIdx.x;
    if (blk < 1024) {
        __shared__ float part[4][64];
        const int b = blk >> 2;
        const int q4 = blk & 3;              // d-range [512*q4, 512*q4+512) of concat(query,frame)
        const int h = t & 63;
        const int g = t >> 6;                // 4 chunks of 128 d's
        const float* src = (q4 < 2 ? query : frame) + (size_t)b * 1024 + (q4 & 1) * 512 + g * 128;
        const float* wrow = W1 + (size_t)(512 + q4 * 512 + g * 128) * 64 + h;
        float acc = 0.f;
#pragma unroll 8
        for (int dd = 0; dd < 128; dd++)
            acc += src[dd] * wrow[(size_t)dd * 64];
        part[g][h] = acc;
        __syncthreads();
        if (t < 64)
            proj_part[((size_t)q4 * NB + b) * 64 + t] =
                part[0][t] + part[1][t] + part[2][t] + part[3][t];
    } else {
        __shared__ float s[32][65];
        const int j = blk - 1024;
        const int k0 = j * 32;
#pragma unroll
        for (int i = 0; i < 8; i++) {
            const int idx = t + 256 * i;
            const int k = idx >> 6, h = idx & 63;
            s[k][h] = W1[(size_t)(k0 + k) * 64 + h];
        }
        __syncthreads();
#pragma unroll
        for (int i = 0; i < 8; i++) {
            const int idx = t + 256 * i;
            const int h = idx >> 5, kk = idx & 31;
            w1kt[(size_t)h * 512 + k0 + kk] = (bf16)s[kk][h];
        }
    }
}

// ---------------- K1: raw scores, block = (batch, P-half), 2 blocks/CU -------
__global__ __launch_bounds__(256, 2) void k1_scores(
    const float* __restrict__ keys, const float* __restrict__ W2,
    const bf16* __restrict__ w1kt, const float* __restrict__ proj_part,
    float* __restrict__ scores_ws)
{
    extern __shared__ char smem[];
    bf16* sk     = (bf16*)smem;                    // [64][520]
    float* projl = (float*)(smem + K1_SK_BYTES);   // [64]
    float* w2l   = projl + 64;                     // [64]

    const int b    = blockIdx.x >> 1;
    const int half = blockIdx.x & 1;
    const int t = threadIdx.x;

    if (t < 64)
        projl[t] = proj_part[(size_t)b * 64 + t]
                 + proj_part[((size_t)NB + b) * 64 + t]
                 + proj_part[((size_t)2 * NB + b) * 64 + t]
                 + proj_part[((size_t)3 * NB + b) * 64 + t];
    else if (t < 128) w2l[t - 64] = W2[t - 64];

    // stage 64 key rows (128KB fp32) -> LDS bf16, coalesced
    const float* kb = keys + (size_t)b * (NP * NK) + (size_t)half * 64 * NK;
    {
        const int rowadd = (t >> 7);
        const int c0 = (t & 127) * 4;
#pragma unroll 8
        for (int i = 0; i < 32; i++) {
            const float4 v = *(const float4*)(kb + (size_t)i * 1024 + t * 4);
            bf16x4 bv;
            bv[0] = (bf16)v.x; bv[1] = (bf16)v.y; bv[2] = (bf16)v.z; bv[3] = (bf16)v.w;
            *(bf16x4*)(sk + (2 * i + rowadd) * SKLD + c0) = bv;
        }
    }
    __syncthreads();

    // GEMM: wave w owns rows [16w,16w+16); C col = h (lane&15), row = q*4+r
    const int w = t >> 6;
    const int lane = t & 63;
    const int m = lane & 15;
    const int q = lane >> 4;

    const bf16* bbase = w1kt + (size_t)m * 512 + q * 8;  // + nt*16*512 + kk*32
    bf16x8 Bc[4], Bn[4];
#pragma unroll
    for (int nt = 0; nt < 4; nt++) Bc[nt] = *(const bf16x8*)(bbase + nt * 8192);
#pragma unroll
    for (int nt = 0; nt < 4; nt++) Bn[nt] = *(const bf16x8*)(bbase + nt * 8192 + 32);

    f32x4 acc[4];
#pragma unroll
    for (int nt = 0; nt < 4; nt++) acc[nt] = (f32x4){0.f, 0.f, 0.f, 0.f};

#pragma unroll
    for (int kk = 0; kk < 16; kk++) {
        const bf16x8 A = *(const bf16x8*)(sk + (w * 16 + m) * SKLD + kk * 32 + q * 8);
        bf16x8 Bf[4];
#pragma unroll
        for (int nt = 0; nt < 4; nt++) Bf[nt] = Bc[nt];
#pragma unroll
        for (int nt = 0; nt < 4; nt++) Bc[nt] = Bn[nt];
        if (kk < 14) {
#pragma unroll
            for (int nt = 0; nt < 4; nt++)
                Bn[nt] = *(const bf16x8*)(bbase + nt * 8192 + (kk + 2) * 32);
        }
#pragma unroll
        for (int nt = 0; nt < 4; nt++)
            acc[nt] = __builtin_amdgcn_mfma_f32_16x16x32_bf16(A, Bf[nt], acc[nt], 0, 0, 0);
    }

    // epilogue: score[p] = sum_h relu(C[p][h]+proj[h]) * W2[h]
    float pr[4] = {0.f, 0.f, 0.f, 0.f};
#pragma unroll
    for (int nt = 0; nt < 4; nt++) {
        const int h = nt * 16 + m;
        const float pv = projl[h];
        const float wv = w2l[h];
#pragma unroll
        for (int r = 0; r < 4; r++)
            pr[r] += fmaxf(acc[nt][r] + pv, 0.f) * wv;
    }
#pragma unroll
    for (int off = 1; off < 16; off <<= 1) {
#pragma unroll
        for (int r = 0; r < 4; r++) pr[r] += __shfl_xor(pr[r], off);
    }
    if (m == 0) {
        const int base = b * 128 + half * 64 + w * 16 + q * 4;
#pragma unroll
        for (int r = 0; r < 4; r++) scores_ws[base + r] = pr[r];
    }
}

// ---------------- K2: masked softmax + context (fp32 keys from L3) ----------
__global__ __launch_bounds__(512) void k2_context(
    const float* __restrict__ keys, const float* __restrict__ frame,
    const int* __restrict__ mask, const float* __restrict__ scores_ws,
    float* __restrict__ out)
{
    __shared__ float s_sc[128];
    __shared__ float s_w[128];
    __shared__ float part[512];

    const int b = blockIdx.x;
    const int t = threadIdx.x;

    if (t < 128) {
        const float raw = scores_ws[b * 128 + t];
        s_sc[t] = (mask[b * 128 + t] == 0) ? -INFINITY : raw;
    }
    __syncthreads();

    if (t < 64) {
        float s0 = s_sc[t], s1 = s_sc[t + 64];
        float mx = fmaxf(s0, s1);
#pragma unroll
        for (int off = 32; off; off >>= 1) mx = fmaxf(mx, __shfl_xor(mx, off));
        float e0 = __expf(s0 - mx), e1 = __expf(s1 - mx);
        float sum = e0 + e1;
#pragma unroll
        for (int off = 32; off; off >>= 1) sum += __shfl_xor(sum, off);
        const float inv = 1.0f / sum;
        s_w[t] = e0 * inv;
        s_w[t + 64] = e1 * inv;
    }
    __syncthreads();

    // weights out (coalesced)
    if (t < 128) out[(size_t)NB * 1536 + b * 128 + t] = s_w[t];

    // context: tg = p-half, tc owns cols 2tc,2tc+1; fp32 keys from global (L3-hot)
    const int tg = t >> 8;
    const int tc = t & 255;
    const float* kb = keys + (size_t)b * (NP * NK);
    float a0 = 0.f, a1 = 0.f;
#pragma unroll 8
    for (int i = 0; i < 64; i++) {
        const int p = tg * 64 + i;
        const float wv = s_w[p];
        const float2 v = *(const float2*)(kb + (size_t)p * 512 + 2 * tc);
        a0 += wv * v.x;
        a1 += wv * v.y;
    }
    if (tg == 1) {
        part[2 * tc] = a0;
        part[2 * tc + 1] = a1;
    }
    __syncthreads();
    if (tg == 0) {
        out[(size_t)b * 1536 + 2 * tc]     = a0 + part[2 * tc];
        out[(size_t)b * 1536 + 2 * tc + 1] = a1 + part[2 * tc + 1];
    }

    // frame passthrough: embeddings[:, 512:1536]
    out[(size_t)b * 1536 + 512 + t] = frame[(size_t)b * 1024 + t];
    out[(size_t)b * 1536 + 1024 + t] = frame[(size_t)b * 1024 + 512 + t];
}

extern "C" void kernel_launch(void* const* d_in, const int* in_sizes, int n_in,
                              void* d_out, int out_size, void* d_ws, size_t ws_size,
                              hipStream_t stream) {
    const float* query = (const float*)d_in[0];
    const float* keys  = (const float*)d_in[1];
    const float* frame = (const float*)d_in[2];
    const int*   mask  = (const int*)d_in[3];
    const float* W1    = (const float*)d_in[4];
    const float* W2    = (const float*)d_in[5];
    float* out = (float*)d_out;

    // ws: [0,64K) W1kT bf16; [64K,320K) proj_part fp32 [4][256][64]; [320K,448K) scores
    bf16*  w1kt      = (bf16*)d_ws;
    float* proj_part = (float*)((char*)d_ws + (64 << 10));
    float* scores_ws = (float*)((char*)d_ws + (320 << 10));

    hipFuncSetAttribute((const void*)k1_scores,
                        hipFuncAttributeMaxDynamicSharedMemorySize, K1_SMEM);

    prep_kernel<<<1040, 256, 0, stream>>>(query, frame, W1, w1kt, proj_part);
    k1_scores<<<512, 256, K1_SMEM, stream>>>(keys, W2, w1kt, proj_part, scores_ws);
    k2_context<<<256, 512, 0, stream>>>(keys, frame, mask, scores_ws, out);
}